// Round 2
// baseline (1154.245 us; speedup 1.0000x reference)
//
#include <hip/hip_runtime.h>
#include <math.h>

#define N_ROWS 262144
#define K_COMP 256
#define D_DIM  128
#define BN 128          // rows per block
#define BD 16           // d-tile
#define XS 132          // padded transposed-x row stride

static __device__ __constant__ float kLOG2PI = 1.8378770664093453f;

// ---------------- prep: B matrices, sigma, per-k constants, zero Q ----------------
__global__ __launch_bounds__(128) void gmm_prep(
    const float* __restrict__ means, const float* __restrict__ log_stds,
    const float* __restrict__ weights,
    float* __restrict__ ivT, float* __restrict__ m2T,
    float* __restrict__ sigma, float* __restrict__ ck, double* __restrict__ wsq)
{
    int k = blockIdx.x;     // 0..255
    int d = threadIdx.x;    // 0..127
    float ls = log_stds[k * D_DIM + d];
    float mu = means[k * D_DIM + d];
    float iv = expf(-2.0f * ls);
    ivT[d * K_COMP + k] = iv;
    m2T[d * K_COMP + k] = -2.0f * mu * iv;
    sigma[k * D_DIM + d] = expf(ls);

    float c = mu * mu * iv;
    float s = ls;
    float w1 = weights[d], w2 = weights[d + 128];
    float wm = fmaxf(w1, w2);

    __shared__ float red[8];
    int lane = d & 63, wv = d >> 6;
    #pragma unroll
    for (int o = 32; o > 0; o >>= 1) {
        c += __shfl_down(c, o, 64);
        s += __shfl_down(s, o, 64);
        wm = fmaxf(wm, __shfl_down(wm, o, 64));
    }
    if (lane == 0) { red[wv] = c; red[2 + wv] = s; red[4 + wv] = wm; }
    __syncthreads();
    float csum = red[0] + red[1];
    float ssum = red[2] + red[3];
    float wmax = fmaxf(red[4], red[5]);
    float we = expf(w1 - wmax) + expf(w2 - wmax);
    #pragma unroll
    for (int o = 32; o > 0; o >>= 1) we += __shfl_down(we, o, 64);
    if (lane == 0) red[6 + wv] = we;
    __syncthreads();
    if (d == 0) {
        float wsum = red[6] + red[7];
        float lw = weights[k] - (wmax + logf(wsum));   // log_softmax(weights)[k]
        ck[k] = -0.5f * (csum + (float)D_DIM * kLOG2PI) - ssum + lw;
        if (k == 0) *wsq = 0.0;
    }
}

// ---------------- main: quad GEMM + softmax/argmax + resample ----------------
__global__ __launch_bounds__(256, 2) void gmm_main(
    const float* __restrict__ x, const float* __restrict__ noise,
    const float* __restrict__ means, const float* __restrict__ sigma,
    const float* __restrict__ ivT, const float* __restrict__ m2T,
    const float* __restrict__ ck,
    float* __restrict__ out_x, float* __restrict__ out_idx, double* __restrict__ wsq)
{
    __shared__ float sIv[BD * K_COMP];
    __shared__ float sM2[BD * K_COMP];
    __shared__ float sX [BD * XS];
    __shared__ float sX2[BD * XS];
    __shared__ float sCk[K_COMP];
    __shared__ int   sIdx[BN];
    __shared__ float sQ;

    const int tid = threadIdx.x;
    const int tx = tid & 15;      // col group: cols q*64 + tx*4 + j
    const int ty = tid >> 4;      // row group: rows ty*8 + rr  (ty 0..15)
    const long n0 = (long)blockIdx.x * BN;

    sCk[tid] = ck[tid];
    if (tid == 0) sQ = 0.0f;

    float acc[8][16];
    #pragma unroll
    for (int r = 0; r < 8; ++r)
        #pragma unroll
        for (int i = 0; i < 16; ++i) acc[r][i] = 0.0f;

    for (int d0 = 0; d0 < D_DIM; d0 += BD) {
        // ---- stage B tiles (coalesced 1KB/wave-instr) ----
        #pragma unroll
        for (int i = 0; i < BD; ++i) {
            sIv[i * K_COMP + tid] = ivT[(d0 + i) * K_COMP + tid];
            sM2[i * K_COMP + tid] = m2T[(d0 + i) * K_COMP + tid];
        }
        // ---- stage x tile transposed + squares: 128 rows x 16 cols ----
        #pragma unroll
        for (int t = tid; t < BN * 4; t += 256) {
            int r  = t >> 2;
            int c4 = (t & 3) * 4;
            float4 xv = *(const float4*)&x[(n0 + r) * D_DIM + d0 + c4];
            float xe[4] = {xv.x, xv.y, xv.z, xv.w};
            #pragma unroll
            for (int j = 0; j < 4; ++j) {
                sX [(c4 + j) * XS + r] = xe[j];
                sX2[(c4 + j) * XS + r] = xe[j] * xe[j];
            }
        }
        __syncthreads();

        #pragma unroll 2
        for (int dd = 0; dd < BD; ++dd) {
            float4 xa  = *(const float4*)&sX [dd * XS + ty * 8];
            float4 xb  = *(const float4*)&sX [dd * XS + ty * 8 + 4];
            float4 x2a = *(const float4*)&sX2[dd * XS + ty * 8];
            float4 x2b = *(const float4*)&sX2[dd * XS + ty * 8 + 4];
            float xe[8]  = {xa.x, xa.y, xa.z, xa.w, xb.x, xb.y, xb.z, xb.w};
            float x2e[8] = {x2a.x, x2a.y, x2a.z, x2a.w, x2b.x, x2b.y, x2b.z, x2b.w};
            #pragma unroll
            for (int q = 0; q < 4; ++q) {
                float4 iv4 = *(const float4*)&sIv[dd * K_COMP + q * 64 + tx * 4];
                float4 m24 = *(const float4*)&sM2[dd * K_COMP + q * 64 + tx * 4];
                float ive[4] = {iv4.x, iv4.y, iv4.z, iv4.w};
                float m2e[4] = {m24.x, m24.y, m24.z, m24.w};
                #pragma unroll
                for (int rr = 0; rr < 8; ++rr)
                    #pragma unroll
                    for (int j = 0; j < 4; ++j)
                        acc[rr][q * 4 + j] += x2e[rr] * ive[j] + xe[rr] * m2e[j];
            }
        }
        __syncthreads();
    }

    // ---- epilogue phase 1: per-row softmax / argmax / Q ----
    float ckv[16];
    #pragma unroll
    for (int q = 0; q < 4; ++q)
        #pragma unroll
        for (int j = 0; j < 4; ++j) ckv[q * 4 + j] = sCk[q * 64 + tx * 4 + j];

    float qacc = 0.0f;
    #pragma unroll 1
    for (int rr = 0; rr < 8; ++rr) {
        float jv[16];
        float m = -INFINITY; int am = 0;
        #pragma unroll
        for (int i = 0; i < 16; ++i) {
            float v = -0.5f * acc[rr][i] + ckv[i];
            jv[i] = v;
            int c = (i >> 2) * 64 + tx * 4 + (i & 3);
            if (v > m || (v == m && c < am)) { m = v; am = c; }
        }
        #pragma unroll
        for (int o = 1; o < 16; o <<= 1) {
            float om = __shfl_xor(m, o, 16);
            int   oa = __shfl_xor(am, o, 16);
            if (om > m || (om == m && oa < am)) { m = om; am = oa; }
        }
        float es = 0.0f, qs = 0.0f;
        #pragma unroll
        for (int i = 0; i < 16; ++i) {
            float e = expf(jv[i] - m);
            es += e; qs += e * jv[i];
        }
        #pragma unroll
        for (int o = 1; o < 16; o <<= 1) {
            es += __shfl_xor(es, o, 16);
            qs += __shfl_xor(qs, o, 16);
        }
        qacc += qs / es;
        if (tx == 0) sIdx[ty * 8 + rr] = am;
    }

    // block Q: each 16-lane group holds identical qacc; butterfly across groups
    qacc += __shfl_xor(qacc, 16, 64);
    qacc += __shfl_xor(qacc, 32, 64);
    if ((tid & 63) == 0) atomicAdd(&sQ, qacc);
    __syncthreads();
    if (tid == 0) atomicAdd(wsq, (double)sQ);

    // ---- epilogue phase 2: wave-contiguous resample writes ----
    const int wv = tid >> 6, lane = tid & 63;
    #pragma unroll 4
    for (int r8 = 0; r8 < 32; ++r8) {
        const int row = wv * 32 + r8;
        const int idx = sIdx[row];
        const long n = n0 + row;
        float2 mv = *(const float2*)&means[idx * D_DIM + lane * 2];
        float2 sv = *(const float2*)&sigma[idx * D_DIM + lane * 2];
        float2 nv = *(const float2*)&noise[n * D_DIM + lane * 2];
        float2 ov;
        ov.x = mv.x + sv.x * nv.x * 0.1f;
        ov.y = mv.y + sv.y * nv.y * 0.1f;
        *(float2*)&out_x[n * D_DIM + lane * 2] = ov;
    }
    if (tid < BN) out_idx[n0 + tid] = (float)sIdx[tid];
}

__global__ void gmm_finalize(const double* __restrict__ wsq, float* __restrict__ out_q)
{
    *out_q = (float)(*wsq * (1.0 / ((double)N_ROWS * (double)K_COMP)));
}

extern "C" void kernel_launch(void* const* d_in, const int* in_sizes, int n_in,
                              void* d_out, int out_size, void* d_ws, size_t ws_size,
                              hipStream_t stream)
{
    const float* x        = (const float*)d_in[0];
    const float* means    = (const float*)d_in[1];
    const float* log_stds = (const float*)d_in[2];
    const float* weights  = (const float*)d_in[3];
    const float* noise    = (const float*)d_in[4];

    float* out_x   = (float*)d_out;                          // [N, D]
    float* out_idx = (float*)d_out + (size_t)N_ROWS * D_DIM; // [N]
    float* out_q   = out_idx + N_ROWS;                       // scalar

    // ws layout (floats): ivT[128*256] | m2T[128*256] | sigma[256*128] | ck[256] | (double) wsq
    float* ws    = (float*)d_ws;
    float* ivT   = ws;
    float* m2T   = ws + 32768;
    float* sigma = ws + 65536;
    float* ck    = ws + 98304;
    double* wsq  = (double*)(ws + 98560);

    hipLaunchKernelGGL(gmm_prep, dim3(K_COMP), dim3(D_DIM), 0, stream,
                       means, log_stds, weights, ivT, m2T, sigma, ck, wsq);
    hipLaunchKernelGGL(gmm_main, dim3(N_ROWS / BN), dim3(256), 0, stream,
                       x, noise, means, sigma, ivT, m2T, ck, out_x, out_idx, wsq);
    hipLaunchKernelGGL(gmm_finalize, dim3(1), dim3(1), 0, stream, wsq, out_q);
}

// Round 3
// 961.410 us; speedup vs baseline: 1.2006x; 1.2006x over previous
//
#include <hip/hip_runtime.h>
#include <math.h>

#define N_ROWS 262144
#define K_COMP 256
#define D_DIM  128
#define BN 64           // rows per block
#define BD 16           // d-tile
#define XS 68           // padded transposed-x row stride (16B-aligned, 2-way alias only)

static __device__ __constant__ float kLOG2PI = 1.8378770664093453f;

// ---------------- prep: B matrices, sigma, per-k constants, zero Q ----------------
__global__ __launch_bounds__(128) void gmm_prep(
    const float* __restrict__ means, const float* __restrict__ log_stds,
    const float* __restrict__ weights,
    float* __restrict__ ivT, float* __restrict__ m2T,
    float* __restrict__ sigma, float* __restrict__ ck, double* __restrict__ wsq)
{
    int k = blockIdx.x;     // 0..255
    int d = threadIdx.x;    // 0..127
    float ls = log_stds[k * D_DIM + d];
    float mu = means[k * D_DIM + d];
    float iv = expf(-2.0f * ls);
    ivT[d * K_COMP + k] = iv;
    m2T[d * K_COMP + k] = -2.0f * mu * iv;
    sigma[k * D_DIM + d] = expf(ls);

    float c = mu * mu * iv;
    float s = ls;
    float w1 = weights[d], w2 = weights[d + 128];
    float wm = fmaxf(w1, w2);

    __shared__ float red[8];
    int lane = d & 63, wv = d >> 6;
    #pragma unroll
    for (int o = 32; o > 0; o >>= 1) {
        c += __shfl_down(c, o, 64);
        s += __shfl_down(s, o, 64);
        wm = fmaxf(wm, __shfl_down(wm, o, 64));
    }
    if (lane == 0) { red[wv] = c; red[2 + wv] = s; red[4 + wv] = wm; }
    __syncthreads();
    float csum = red[0] + red[1];
    float ssum = red[2] + red[3];
    float wmax = fmaxf(red[4], red[5]);
    float we = expf(w1 - wmax) + expf(w2 - wmax);
    #pragma unroll
    for (int o = 32; o > 0; o >>= 1) we += __shfl_down(we, o, 64);
    if (lane == 0) red[6 + wv] = we;
    __syncthreads();
    if (d == 0) {
        float wsum = red[6] + red[7];
        float lw = weights[k] - (wmax + logf(wsum));   // log_softmax(weights)[k]
        ck[k] = -0.5f * (csum + (float)D_DIM * kLOG2PI) - ssum + lw;
        if (k == 0) *wsq = 0.0;
    }
}

// ---------------- main: quad GEMM + softmax/argmax + resample ----------------
// 256 threads, 64 rows x 256 cols per block, 8x8 per-thread tile.
// launch_bounds(256,4): cap total regs at 128 -> 4 waves/SIMD, no spill.
__global__ __launch_bounds__(256, 4) void gmm_main(
    const float* __restrict__ x, const float* __restrict__ noise,
    const float* __restrict__ means, const float* __restrict__ sigma,
    const float* __restrict__ ivT, const float* __restrict__ m2T,
    const float* __restrict__ ck,
    float* __restrict__ out_x, float* __restrict__ out_idx, double* __restrict__ wsq)
{
    __shared__ float sIv[BD * K_COMP];
    __shared__ float sM2[BD * K_COMP];
    __shared__ float sX [BD * XS];
    __shared__ float sCk[K_COMP];
    __shared__ int   sIdx[BN];
    __shared__ float sQ;

    const int tid = threadIdx.x;
    const int tx = tid & 31;      // col group: cols h*128 + tx*4 + j
    const int ty = tid >> 5;      // row group: rows ty*8 + rr  (ty 0..7)
    const long n0 = (long)blockIdx.x * BN;

    sCk[tid] = ck[tid];
    if (tid == 0) sQ = 0.0f;

    float acc[8][8];
    #pragma unroll
    for (int r = 0; r < 8; ++r)
        #pragma unroll
        for (int i = 0; i < 8; ++i) acc[r][i] = 0.0f;

    const int xr  = tid >> 2;          // staging row 0..63
    const int xc4 = (tid & 3) * 4;     // staging col 0,4,8,12

    #pragma unroll 1
    for (int d0 = 0; d0 < D_DIM; d0 += BD) {
        // ---- stage B tiles: float2 coalesced, 8 iters per array ----
        {
            const float2* gIv = (const float2*)&ivT[d0 * K_COMP];
            const float2* gM2 = (const float2*)&m2T[d0 * K_COMP];
            float2* lIv = (float2*)sIv;
            float2* lM2 = (float2*)sM2;
            #pragma unroll
            for (int it = 0; it < 8; ++it) {
                lIv[tid + it * 256] = gIv[tid + it * 256];
                lM2[tid + it * 256] = gM2[tid + it * 256];
            }
        }
        // ---- stage x tile transposed (squares computed later in regs) ----
        {
            float4 xv = *(const float4*)&x[(n0 + xr) * D_DIM + d0 + xc4];
            float xe[4] = {xv.x, xv.y, xv.z, xv.w};
            #pragma unroll
            for (int j = 0; j < 4; ++j)
                sX[(xc4 + j) * XS + xr] = xe[j];
        }
        __syncthreads();

        #pragma unroll 4
        for (int dd = 0; dd < BD; ++dd) {
            float4 xa = *(const float4*)&sX[dd * XS + ty * 8];
            float4 xb = *(const float4*)&sX[dd * XS + ty * 8 + 4];
            float xe[8]  = {xa.x, xa.y, xa.z, xa.w, xb.x, xb.y, xb.z, xb.w};
            float x2e[8];
            #pragma unroll
            for (int r = 0; r < 8; ++r) x2e[r] = xe[r] * xe[r];

            float4 iva = *(const float4*)&sIv[dd * K_COMP + tx * 4];
            float4 ivb = *(const float4*)&sIv[dd * K_COMP + 128 + tx * 4];
            float4 m2a = *(const float4*)&sM2[dd * K_COMP + tx * 4];
            float4 m2b = *(const float4*)&sM2[dd * K_COMP + 128 + tx * 4];
            float ive[8] = {iva.x, iva.y, iva.z, iva.w, ivb.x, ivb.y, ivb.z, ivb.w};
            float m2e[8] = {m2a.x, m2a.y, m2a.z, m2a.w, m2b.x, m2b.y, m2b.z, m2b.w};

            #pragma unroll
            for (int rr = 0; rr < 8; ++rr)
                #pragma unroll
                for (int i = 0; i < 8; ++i)
                    acc[rr][i] += x2e[rr] * ive[i] + xe[rr] * m2e[i];
        }
        __syncthreads();
    }

    // ---- epilogue phase 1: per-row softmax / argmax / Q ----
    float ckv[8];
    #pragma unroll
    for (int h = 0; h < 2; ++h)
        #pragma unroll
        for (int j = 0; j < 4; ++j) ckv[h * 4 + j] = sCk[h * 128 + tx * 4 + j];

    float qacc = 0.0f;
    #pragma unroll 1
    for (int rr = 0; rr < 8; ++rr) {
        float jv[8];
        float m = -INFINITY; int am = 0;
        #pragma unroll
        for (int i = 0; i < 8; ++i) {
            float v = -0.5f * acc[rr][i] + ckv[i];
            jv[i] = v;
            int c = (i >> 2) * 128 + tx * 4 + (i & 3);
            if (v > m || (v == m && c < am)) { m = v; am = c; }
        }
        #pragma unroll
        for (int o = 1; o < 32; o <<= 1) {
            float om = __shfl_xor(m, o, 32);
            int   oa = __shfl_xor(am, o, 32);
            if (om > m || (om == m && oa < am)) { m = om; am = oa; }
        }
        float es = 0.0f, qs = 0.0f;
        #pragma unroll
        for (int i = 0; i < 8; ++i) {
            float e = expf(jv[i] - m);
            es += e; qs += e * jv[i];
        }
        #pragma unroll
        for (int o = 1; o < 32; o <<= 1) {
            es += __shfl_xor(es, o, 32);
            qs += __shfl_xor(qs, o, 32);
        }
        qacc += qs / es;
        if (tx == 0) sIdx[ty * 8 + rr] = am;
    }

    // Q: both 32-lane groups of a wave hold their own group sums; fold, then block-reduce
    qacc += __shfl_xor(qacc, 32, 64);
    if ((tid & 63) == 0) atomicAdd(&sQ, qacc);
    __syncthreads();
    if (tid == 0) atomicAdd(wsq, (double)sQ);

    // ---- epilogue phase 2: wave-contiguous resample writes ----
    const int wv = tid >> 6, lane = tid & 63;
    #pragma unroll 4
    for (int r16 = 0; r16 < 16; ++r16) {
        const int row = wv * 16 + r16;
        const int idx = sIdx[row];
        const long n = n0 + row;
        float2 mv = *(const float2*)&means[idx * D_DIM + lane * 2];
        float2 sv = *(const float2*)&sigma[idx * D_DIM + lane * 2];
        float2 nv = *(const float2*)&noise[n * D_DIM + lane * 2];
        float2 ov;
        ov.x = mv.x + sv.x * nv.x * 0.1f;
        ov.y = mv.y + sv.y * nv.y * 0.1f;
        *(float2*)&out_x[n * D_DIM + lane * 2] = ov;
    }
    if (tid < BN) out_idx[n0 + tid] = (float)sIdx[tid];
}

__global__ void gmm_finalize(const double* __restrict__ wsq, float* __restrict__ out_q)
{
    *out_q = (float)(*wsq * (1.0 / ((double)N_ROWS * (double)K_COMP)));
}

extern "C" void kernel_launch(void* const* d_in, const int* in_sizes, int n_in,
                              void* d_out, int out_size, void* d_ws, size_t ws_size,
                              hipStream_t stream)
{
    const float* x        = (const float*)d_in[0];
    const float* means    = (const float*)d_in[1];
    const float* log_stds = (const float*)d_in[2];
    const float* weights  = (const float*)d_in[3];
    const float* noise    = (const float*)d_in[4];

    float* out_x   = (float*)d_out;                          // [N, D]
    float* out_idx = (float*)d_out + (size_t)N_ROWS * D_DIM; // [N]
    float* out_q   = out_idx + N_ROWS;                       // scalar

    // ws layout (floats): ivT[128*256] | m2T[128*256] | sigma[256*128] | ck[256] | (double) wsq
    float* ws    = (float*)d_ws;
    float* ivT   = ws;
    float* m2T   = ws + 32768;
    float* sigma = ws + 65536;
    float* ck    = ws + 98304;
    double* wsq  = (double*)(ws + 98560);

    hipLaunchKernelGGL(gmm_prep, dim3(K_COMP), dim3(D_DIM), 0, stream,
                       means, log_stds, weights, ivT, m2T, sigma, ck, wsq);
    hipLaunchKernelGGL(gmm_main, dim3(N_ROWS / BN), dim3(256), 0, stream,
                       x, noise, means, sigma, ivT, m2T, ck, out_x, out_idx, wsq);
    hipLaunchKernelGGL(gmm_finalize, dim3(1), dim3(1), 0, stream, wsq, out_q);
}